// Round 12
// baseline (512.180 us; speedup 1.0000x reference)
//
#include <hip/hip_runtime.h>
#include <hip/hip_bf16.h>

// ============================ EVIDENCE LOG ============================
//  R0 stub: err0 24.125 (= max|bf16-rounded ref0|; comparison ref is bf16-
//     rounded via floor_eps_k path, but the BUFFER is fp32 — see R11).
//  R1: bf16 reads of float inputs -> NaN => inputs fp32; rows/cols int32.
//  R2-R10: every semantic/geometry variant, written as bf16 -> err 35-40,
//     flip-insensitive "full decorrelation".
//  R11 SENTINEL (bf16 256 at elem 0, zeros elsewhere): err0 = 24.125 EXACTLY
//     = stub. Under a bf16 read this is impossible (err would be >= 231).
//     => d_out is FP32. bf16 writes pack 2 values/word; fp32 read gives
//     mine[2j+1] at position j -> perfect decorrelation regardless of
//     semantics. Explains ALL eleven prior results, incl. the exact stub
//     repeat (sentinel's low-half 0x4380 = denorm ~0; all other words 0.0).
//  => R2's semantics (faithful shown jnp reference) were never actually
//     tested. This round: R2 semantics + fp32 output, no ws needed.
// ======================================================================

// Kernel 1: dense base (mobility + covariate) written DIRECTLY into fp32
// d_out, initializing every element over the 0xAA poison.
// Layout [Tp, n] time-major, outputs concatenated [out0 | out1].
__global__ void base_kernel(const float* __restrict__ M,   // [NMOB, T, NC]
                            const float* __restrict__ cov, // [NCOV, NC]
                            const float* __restrict__ mu,  // [NMOB, P]
                            const float* __restrict__ nu,  // [NMOB, P]
                            const float* __restrict__ ups, // [NCOV]
                            const float* __restrict__ zet, // [NCOV]
                            float* __restrict__ out0,
                            float* __restrict__ out1,
                            int T, int NC, int NMOB, int NCOV, int P, int TPn) {
    int idx = blockIdx.x * blockDim.x + threadIdx.x;
    if (idx >= TPn * NC) return;
    int i = idx / NC;
    int c = idx - i * NC;

    float mobc = 0.f, mobd = 0.f;
    for (int k = 0; k < NMOB; ++k) {
        for (int tau = 0; tau < P; ++tau) {
            float m = M[((size_t)k * T + i + tau) * NC + c];
            mobc += m * mu[k * P + tau];
            mobd += m * nu[k * P + tau];
        }
    }
    float covc = 0.f, covd = 0.f;
    for (int j = 0; j < NCOV; ++j) {
        float cv = cov[(size_t)j * NC + c];
        covc += cv * ups[j];
        covd += cv * zet[j];
    }
    out0[idx] = mobc + covc;
    out1[idx] = mobd + covd;
}

// Kernel 2: sparse scatter, shown einsum semantics (x @ B):
//   out0[i, cols[k]] += (C[i, rows[k]] + C[i+1, rows[k]]) * B_nz[k]
//   out1[i, cols[k]] += Csum * H_nz[k] + Dsum * A_nz[k]
// Same stream => runs after base_kernel. One thread per (i,k), i-major:
// coalesced index/nz loads. Duplicates sum via atomics (.at[].add).
__global__ void sparse_kernel(const float* __restrict__ C,   // [T, NC]
                              const float* __restrict__ D,   // [T, NC]
                              const float* __restrict__ Bnz,
                              const float* __restrict__ Anz,
                              const float* __restrict__ Hnz,
                              const int*  __restrict__ rows,
                              const int*  __restrict__ cols,
                              float* __restrict__ out0,
                              float* __restrict__ out1,
                              int NC, int NNZ, int P, int TPn) {
    long long idx = (long long)blockIdx.x * blockDim.x + threadIdx.x;
    if (idx >= (long long)TPn * NNZ) return;
    int i = (int)(idx / NNZ);
    int k = (int)(idx - (long long)i * NNZ);

    int g = rows[k];   // gather (contracted axis of x@B)
    int s = cols[k];   // scatter (output axis)

    float csum = 0.f, dsum = 0.f;
    for (int tau = 0; tau < P; ++tau) {
        csum += C[(size_t)(i + tau) * NC + g];
        dsum += D[(size_t)(i + tau) * NC + g];
    }

    atomicAdd(&out0[(size_t)i * NC + s], csum * Bnz[k]);
    atomicAdd(&out1[(size_t)i * NC + s], csum * Hnz[k] + dsum * Anz[k]);
}

extern "C" void kernel_launch(void* const* d_in, const int* in_sizes, int n_in,
                              void* d_out, int out_size, void* d_ws, size_t ws_size,
                              hipStream_t stream) {
    const float* C    = (const float*)d_in[0];
    const float* D    = (const float*)d_in[1];
    const float* M    = (const float*)d_in[2];
    const float* cov  = (const float*)d_in[3];
    const float* Bnz  = (const float*)d_in[4];
    const float* Anz  = (const float*)d_in[5];
    const float* Hnz  = (const float*)d_in[6];
    const float* mu   = (const float*)d_in[7];
    const float* nu   = (const float*)d_in[8];
    const float* ups  = (const float*)d_in[9];
    const float* zet  = (const float*)d_in[10];
    const int*  rows  = (const int*)d_in[11];
    const int*  cols  = (const int*)d_in[12];

    int NCOV = in_sizes[9];                 // 10
    int NC   = in_sizes[3] / NCOV;          // 3144
    int T    = in_sizes[0] / NC;            // 156
    int NMOB = in_sizes[2] / in_sizes[0];   // 6
    int P    = in_sizes[7] / NMOB;          // 2
    int NNZ  = in_sizes[11];                // 31440
    int TPn  = T - P;                       // 154

    float* out0 = (float*)d_out;            // FP32 output (R11 sentinel proof)
    float* out1 = out0 + (size_t)TPn * NC;

    int base_n = TPn * NC;
    base_kernel<<<(base_n + 255) / 256, 256, 0, stream>>>(
        M, cov, mu, nu, ups, zet, out0, out1, T, NC, NMOB, NCOV, P, TPn);

    long long sp_n = (long long)TPn * NNZ;
    sparse_kernel<<<(int)((sp_n + 255) / 256), 256, 0, stream>>>(
        C, D, Bnz, Anz, Hnz, rows, cols, out0, out1, NC, NNZ, P, TPn);
}

// Round 13
// 197.475 us; speedup vs baseline: 2.5937x; 2.5937x over previous
//
#include <hip/hip_runtime.h>

// ============================ EVIDENCE LOG ============================
//  R0-R11: channel debugging saga. Key facts: inputs fp32 time-major as
//    shown; rows/cols int32; d_out is FP32 (R11 sentinel proof; the bf16
//    branch in the traceback is untaken code); output = [out0|out1] each
//    [Tp, n] flat; shown-jnp semantics are CORRECT (R12 passed, 0.0625).
//  R12 (scatter-atomic version): PASS, 512 us. rocprof: sparse_kernel
//    421 us, WRITE_SIZE 282 MB (!) vs 3.9 MB ideal -> device-scope fp32
//    atomics RMW at memory side (8 non-coherent XCD L2s), 72x write
//    amplification. VALUBusy 1.9%, MfmaUtil 0, HBM 9%. Pure atomic latency.
//  THIS ROUND: invert scatter->gather via on-device CSR (degree ~10 per
//    county), fuse base+sparse into one kernel with plain stores.
// ======================================================================

#define SCAN_TH 1024

// ---- CSR build (all tiny; ~10 us total) ----

__global__ void csr_zero(int* __restrict__ counts, int NC) {
    int i = blockIdx.x * blockDim.x + threadIdx.x;
    if (i < NC) counts[i] = 0;
}

__global__ void csr_hist(const int* __restrict__ cols, int* __restrict__ counts, int NNZ) {
    int k = blockIdx.x * blockDim.x + threadIdx.x;
    if (k < NNZ) atomicAdd(&counts[cols[k]], 1);
}

// Single block of 1024 threads: exclusive scan of counts -> offsets, copy to
// cursor, offsets[NC] = total.
__global__ void csr_scan(const int* __restrict__ counts, int* __restrict__ offsets,
                         int* __restrict__ cursor, int NC) {
    __shared__ int ssum[SCAN_TH];
    int t = threadIdx.x;
    int chunk = (NC + SCAN_TH - 1) / SCAN_TH;
    int beg = t * chunk, end = min(beg + chunk, NC);

    int local = 0;
    for (int j = beg; j < end; ++j) local += counts[j];
    ssum[t] = local;
    __syncthreads();

    // Hillis-Steele inclusive scan (read-all / sync / write / sync).
    for (int off = 1; off < SCAN_TH; off <<= 1) {
        int tmp = (t >= off) ? ssum[t - off] : 0;
        __syncthreads();
        ssum[t] += tmp;
        __syncthreads();
    }

    int run = ssum[t] - local;   // exclusive prefix of this thread's chunk
    for (int j = beg; j < end; ++j) {
        offsets[j] = run;
        cursor[j]  = run;
        run += counts[j];
    }
    if (t == SCAN_TH - 1) offsets[NC] = ssum[SCAN_TH - 1];
}

__global__ void csr_fill(const int* __restrict__ rows, const int* __restrict__ cols,
                         const float* __restrict__ Bnz, const float* __restrict__ Anz,
                         const float* __restrict__ Hnz,
                         int* __restrict__ cursor,
                         int* __restrict__ eg, float* __restrict__ eb,
                         float* __restrict__ ea, float* __restrict__ eh, int NNZ) {
    int k = blockIdx.x * blockDim.x + threadIdx.x;
    if (k >= NNZ) return;
    int s = cols[k];                      // scatter target (output county)
    int pos = atomicAdd(&cursor[s], 1);   // bucket order nondet; fp32 sum noise ~1e-7, fine
    eg[pos] = rows[k];                    // gather county
    eb[pos] = Bnz[k];
    ea[pos] = Anz[k];
    eh[pos] = Hnz[k];
}

// ---- Fused main kernel: base (mob + cov) + CSR gather, plain stores ----
// idx = i*NC + c, c fast: M/cov/offset loads and out stores all coalesced.
// Edge gathers (~10/thread) are random within L2-resident C/D (3.9 MB) and
// the 0.5 MB edge table (reused across all 154 i values).
__global__ void fused_kernel(const float* __restrict__ C,   // [T, NC]
                             const float* __restrict__ D,   // [T, NC]
                             const float* __restrict__ M,   // [NMOB, T, NC]
                             const float* __restrict__ cov, // [NCOV, NC]
                             const float* __restrict__ mu,  // [NMOB, P]
                             const float* __restrict__ nu,  // [NMOB, P]
                             const float* __restrict__ ups, // [NCOV]
                             const float* __restrict__ zet, // [NCOV]
                             const int* __restrict__ offsets,
                             const int* __restrict__ eg,
                             const float* __restrict__ eb,
                             const float* __restrict__ ea,
                             const float* __restrict__ eh,
                             float* __restrict__ out0,
                             float* __restrict__ out1,
                             int T, int NC, int NMOB, int NCOV, int P, int TPn) {
    int idx = blockIdx.x * blockDim.x + threadIdx.x;
    if (idx >= TPn * NC) return;
    int i = idx / NC;
    int c = idx - i * NC;

    float acc0 = 0.f, acc1 = 0.f;

    // mobility terms (coalesced in c)
    for (int k = 0; k < NMOB; ++k) {
        for (int tau = 0; tau < P; ++tau) {
            float m = M[((size_t)k * T + i + tau) * NC + c];
            acc0 += m * mu[k * P + tau];
            acc1 += m * nu[k * P + tau];
        }
    }
    // covariate terms (coalesced in c)
    for (int j = 0; j < NCOV; ++j) {
        float cv = cov[(size_t)j * NC + c];
        acc0 += cv * ups[j];
        acc1 += cv * zet[j];
    }
    // sparse gather: out0[i,c] += sum_edges (C[i,g]+C[i+1,g])*b, etc.
    int e0 = offsets[c], e1 = offsets[c + 1];
    for (int e = e0; e < e1; ++e) {
        int g = eg[e];
        float csum = 0.f, dsum = 0.f;
        for (int tau = 0; tau < P; ++tau) {
            csum += C[(size_t)(i + tau) * NC + g];
            dsum += D[(size_t)(i + tau) * NC + g];
        }
        acc0 += csum * eb[e];
        acc1 += csum * eh[e] + dsum * ea[e];
    }

    out0[idx] = acc0;
    out1[idx] = acc1;
}

extern "C" void kernel_launch(void* const* d_in, const int* in_sizes, int n_in,
                              void* d_out, int out_size, void* d_ws, size_t ws_size,
                              hipStream_t stream) {
    const float* C    = (const float*)d_in[0];
    const float* D    = (const float*)d_in[1];
    const float* M    = (const float*)d_in[2];
    const float* cov  = (const float*)d_in[3];
    const float* Bnz  = (const float*)d_in[4];
    const float* Anz  = (const float*)d_in[5];
    const float* Hnz  = (const float*)d_in[6];
    const float* mu   = (const float*)d_in[7];
    const float* nu   = (const float*)d_in[8];
    const float* ups  = (const float*)d_in[9];
    const float* zet  = (const float*)d_in[10];
    const int*  rows  = (const int*)d_in[11];
    const int*  cols  = (const int*)d_in[12];

    int NCOV = in_sizes[9];                 // 10
    int NC   = in_sizes[3] / NCOV;          // 3144
    int T    = in_sizes[0] / NC;            // 156
    int NMOB = in_sizes[2] / in_sizes[0];   // 6
    int P    = in_sizes[7] / NMOB;          // 2
    int NNZ  = in_sizes[11];                // 31440
    int TPn  = T - P;                       // 154

    float* out0 = (float*)d_out;            // fp32 (R11 proof)
    float* out1 = out0 + (size_t)TPn * NC;

    // ws carve-up (all 4-byte aligned): ints then floats, ~540 KB total.
    int*   counts  = (int*)d_ws;
    int*   offsets = counts + NC;
    int*   cursor  = offsets + (NC + 1);
    int*   eg      = cursor + NC;
    float* eb      = (float*)(eg + NNZ);
    float* ea      = eb + NNZ;
    float* eh      = ea + NNZ;

    const int BS = 256;
    csr_zero<<<(NC + BS - 1) / BS, BS, 0, stream>>>(counts, NC);
    csr_hist<<<(NNZ + BS - 1) / BS, BS, 0, stream>>>(cols, counts, NNZ);
    csr_scan<<<1, SCAN_TH, 0, stream>>>(counts, offsets, cursor, NC);
    csr_fill<<<(NNZ + BS - 1) / BS, BS, 0, stream>>>(
        rows, cols, Bnz, Anz, Hnz, cursor, eg, eb, ea, eh, NNZ);

    int n = TPn * NC;
    fused_kernel<<<(n + BS - 1) / BS, BS, 0, stream>>>(
        C, D, M, cov, mu, nu, ups, zet, offsets, eg, eb, ea, eh,
        out0, out1, T, NC, NMOB, NCOV, P, TPn);
}

// Round 14
// 194.329 us; speedup vs baseline: 2.6356x; 1.0162x over previous
//
#include <hip/hip_runtime.h>

// ============================ EVIDENCE LOG ============================
//  R0-R11: harness-channel saga. Facts: inputs fp32 time-major as shown;
//    rows/cols int32; d_out FP32 (R11 sentinel); out = [out0|out1], each
//    [Tp,n] flat; shown-jnp semantics CORRECT (R12 pass, absmax 0.0625).
//  R12 scatter-atomic: 512 us; WRITE 282 MB = device-scope atomic RMW amp.
//  R13 CSR-gather fused: 197 us. fused=105 us (VALUBusy 7%, HBM 4%,
//    FETCH 31 MB): latency-bound, ~102 scalar loads/thread, runtime edge
//    loop not pipelined. ~92 us = 4 tiny CSR dispatches + launch overhead.
//  THIS ROUND: (1) single-WG CSR build (1 dispatch, LDS hist+scan+fill);
//    (2) fused kernel: float4-packed edges + i-tile x4 (template<IT,P>),
//    per-pair loads 102 -> ~38, fully unrolled for MLP.
// ======================================================================

#define CSR_TH 1024
#define MAXNC  4096   // NC = 3144 (verified all 13 rounds)

// One workgroup builds the whole CSR: histogram of cols in LDS, chunked
// Hillis-Steele exclusive scan, then fill of float4 edges (g,B,A,H).
__global__ __launch_bounds__(CSR_TH)
void csr_build(const int* __restrict__ rows, const int* __restrict__ cols,
               const float* __restrict__ Bnz, const float* __restrict__ Anz,
               const float* __restrict__ Hnz,
               int* __restrict__ offsets,      // [NC+1]
               float4* __restrict__ edges,     // [NNZ]
               int NC, int NNZ) {
    __shared__ int s_cnt[MAXNC];
    __shared__ int s_part[CSR_TH];
    int t = threadIdx.x;

    for (int j = t; j < NC; j += CSR_TH) s_cnt[j] = 0;
    __syncthreads();
    for (int k = t; k < NNZ; k += CSR_TH) atomicAdd(&s_cnt[cols[k]], 1);
    __syncthreads();

    // chunked exclusive scan over NC entries
    int chunk = (NC + CSR_TH - 1) / CSR_TH;
    int beg = t * chunk, end = min(beg + chunk, NC);
    int local = 0;
    for (int j = beg; j < end; ++j) local += s_cnt[j];
    s_part[t] = local;
    __syncthreads();
    for (int off = 1; off < CSR_TH; off <<= 1) {
        int v = (t >= off) ? s_part[t - off] : 0;
        __syncthreads();
        s_part[t] += v;
        __syncthreads();
    }
    int run = s_part[t] - local;   // exclusive prefix of this chunk
    for (int j = beg; j < end; ++j) {
        offsets[j] = run;
        int cj = s_cnt[j];
        s_cnt[j] = run;            // becomes the fill cursor
        run += cj;
    }
    if (t == CSR_TH - 1) offsets[NC] = s_part[CSR_TH - 1];
    __syncthreads();

    // fill (bucket order nondet -> fp32 sum order noise ~1e-7, irrelevant)
    for (int k = t; k < NNZ; k += CSR_TH) {
        int s = cols[k];
        int pos = atomicAdd(&s_cnt[s], 1);
        edges[pos] = make_float4(__int_as_float(rows[k]), Bnz[k], Anz[k], Hnz[k]);
    }
}

// Fused main kernel, IT time steps per thread, compile-time P.
// idx = iTile*NC + c (c fast: M/cov loads + out stores coalesced).
// Edge loop: 1 float4 + (IT+P-1) C + (IT+P-1) D loads per edge, serving
// IT output pairs. Fully unrolled -> long independent-load runs.
template<int IT, int PP>
__global__ void fused_tiled(const float* __restrict__ C,   // [T, NC]
                            const float* __restrict__ D,   // [T, NC]
                            const float* __restrict__ M,   // [NMOB, T, NC]
                            const float* __restrict__ cov, // [NCOV, NC]
                            const float* __restrict__ mu,  // [NMOB, P]
                            const float* __restrict__ nu,  // [NMOB, P]
                            const float* __restrict__ ups, // [NCOV]
                            const float* __restrict__ zet, // [NCOV]
                            const int* __restrict__ offsets,
                            const float4* __restrict__ edges,
                            float* __restrict__ out0,
                            float* __restrict__ out1,
                            int T, int NC, int NMOB, int NCOV, int TPn, int nTiles) {
    int idx = blockIdx.x * blockDim.x + threadIdx.x;
    if (idx >= nTiles * NC) return;
    int iT = idx / NC;
    int c  = idx - iT * NC;
    int i0 = iT * IT;
    int nv = TPn - i0; if (nv > IT) nv = IT;   // valid outputs this tile
    int nl = nv + PP - 1;                       // time-span of loads

    float a0[IT], a1[IT];
#pragma unroll
    for (int ii = 0; ii < IT; ++ii) { a0[ii] = 0.f; a1[ii] = 0.f; }

    // covariate term (identical for all i in the tile)
    float cv0 = 0.f, cv1 = 0.f;
    for (int j = 0; j < NCOV; ++j) {
        float cv = cov[(size_t)j * NC + c];
        cv0 += cv * ups[j];
        cv1 += cv * zet[j];
    }
#pragma unroll
    for (int ii = 0; ii < IT; ++ii) { a0[ii] += cv0; a1[ii] += cv1; }

    // mobility terms: IT+PP-1 M-loads per k serve IT outputs x PP taus
    for (int k = 0; k < NMOB; ++k) {
        float Mv[IT + PP - 1];
#pragma unroll
        for (int tt = 0; tt < IT + PP - 1; ++tt)
            Mv[tt] = (tt < nl) ? M[((size_t)k * T + i0 + tt) * NC + c] : 0.f;
        float cmu[PP], cnu[PP];
#pragma unroll
        for (int tau = 0; tau < PP; ++tau) {
            cmu[tau] = mu[k * PP + tau];
            cnu[tau] = nu[k * PP + tau];
        }
#pragma unroll
        for (int ii = 0; ii < IT; ++ii)
#pragma unroll
            for (int tau = 0; tau < PP; ++tau) {
                a0[ii] += Mv[ii + tau] * cmu[tau];
                a1[ii] += Mv[ii + tau] * cnu[tau];
            }
    }

    // sparse term: out0 += Csum*B ; out1 += Csum*H + Dsum*A
    int e0 = offsets[c], e1 = offsets[c + 1];
    for (int e = e0; e < e1; ++e) {
        float4 E = edges[e];           // (g, B, A, H)
        int g = __float_as_int(E.x);
        float Cv[IT + PP - 1], Dv[IT + PP - 1];
#pragma unroll
        for (int tt = 0; tt < IT + PP - 1; ++tt) {
            if (tt < nl) {
                Cv[tt] = C[(size_t)(i0 + tt) * NC + g];
                Dv[tt] = D[(size_t)(i0 + tt) * NC + g];
            } else { Cv[tt] = 0.f; Dv[tt] = 0.f; }
        }
#pragma unroll
        for (int ii = 0; ii < IT; ++ii) {
            float cs = 0.f, ds = 0.f;
#pragma unroll
            for (int tau = 0; tau < PP; ++tau) { cs += Cv[ii + tau]; ds += Dv[ii + tau]; }
            a0[ii] += cs * E.y;
            a1[ii] += cs * E.w + ds * E.z;
        }
    }

    for (int ii = 0; ii < nv; ++ii) {
        out0[(size_t)(i0 + ii) * NC + c] = a0[ii];
        out1[(size_t)(i0 + ii) * NC + c] = a1[ii];
    }
}

// Generic fallback (runtime P), R13 structure — only used if P != 2.
__global__ void fused_generic(const float* __restrict__ C, const float* __restrict__ D,
                              const float* __restrict__ M, const float* __restrict__ cov,
                              const float* __restrict__ mu, const float* __restrict__ nu,
                              const float* __restrict__ ups, const float* __restrict__ zet,
                              const int* __restrict__ offsets, const float4* __restrict__ edges,
                              float* __restrict__ out0, float* __restrict__ out1,
                              int T, int NC, int NMOB, int NCOV, int P, int TPn) {
    int idx = blockIdx.x * blockDim.x + threadIdx.x;
    if (idx >= TPn * NC) return;
    int i = idx / NC;
    int c = idx - i * NC;
    float acc0 = 0.f, acc1 = 0.f;
    for (int k = 0; k < NMOB; ++k)
        for (int tau = 0; tau < P; ++tau) {
            float m = M[((size_t)k * T + i + tau) * NC + c];
            acc0 += m * mu[k * P + tau];
            acc1 += m * nu[k * P + tau];
        }
    for (int j = 0; j < NCOV; ++j) {
        float cv = cov[(size_t)j * NC + c];
        acc0 += cv * ups[j];
        acc1 += cv * zet[j];
    }
    int e0 = offsets[c], e1 = offsets[c + 1];
    for (int e = e0; e < e1; ++e) {
        float4 E = edges[e];
        int g = __float_as_int(E.x);
        float cs = 0.f, ds = 0.f;
        for (int tau = 0; tau < P; ++tau) {
            cs += C[(size_t)(i + tau) * NC + g];
            ds += D[(size_t)(i + tau) * NC + g];
        }
        acc0 += cs * E.y;
        acc1 += cs * E.w + ds * E.z;
    }
    out0[idx] = acc0;
    out1[idx] = acc1;
}

extern "C" void kernel_launch(void* const* d_in, const int* in_sizes, int n_in,
                              void* d_out, int out_size, void* d_ws, size_t ws_size,
                              hipStream_t stream) {
    const float* C    = (const float*)d_in[0];
    const float* D    = (const float*)d_in[1];
    const float* M    = (const float*)d_in[2];
    const float* cov  = (const float*)d_in[3];
    const float* Bnz  = (const float*)d_in[4];
    const float* Anz  = (const float*)d_in[5];
    const float* Hnz  = (const float*)d_in[6];
    const float* mu   = (const float*)d_in[7];
    const float* nu   = (const float*)d_in[8];
    const float* ups  = (const float*)d_in[9];
    const float* zet  = (const float*)d_in[10];
    const int*  rows  = (const int*)d_in[11];
    const int*  cols  = (const int*)d_in[12];

    int NCOV = in_sizes[9];                 // 10
    int NC   = in_sizes[3] / NCOV;          // 3144
    int T    = in_sizes[0] / NC;            // 156
    int NMOB = in_sizes[2] / in_sizes[0];   // 6
    int P    = in_sizes[7] / NMOB;          // 2
    int NNZ  = in_sizes[11];                // 31440
    int TPn  = T - P;                       // 154

    float* out0 = (float*)d_out;            // fp32 (R11 proof)
    float* out1 = out0 + (size_t)TPn * NC;

    // ws: float4 edges first (16B-aligned at base), then offsets.
    float4* edges   = (float4*)d_ws;
    int*    offsets = (int*)(edges + NNZ);

    csr_build<<<1, CSR_TH, 0, stream>>>(rows, cols, Bnz, Anz, Hnz,
                                        offsets, edges, NC, NNZ);

    const int BS = 256;
    if (P == 2) {
        constexpr int IT = 4;
        int nTiles = (TPn + IT - 1) / IT;
        int n = nTiles * NC;
        fused_tiled<IT, 2><<<(n + BS - 1) / BS, BS, 0, stream>>>(
            C, D, M, cov, mu, nu, ups, zet, offsets, edges,
            out0, out1, T, NC, NMOB, NCOV, TPn, nTiles);
    } else {
        int n = TPn * NC;
        fused_generic<<<(n + BS - 1) / BS, BS, 0, stream>>>(
            C, D, M, cov, mu, nu, ups, zet, offsets, edges,
            out0, out1, T, NC, NMOB, NCOV, P, TPn);
    }
}

// Round 15
// 149.265 us; speedup vs baseline: 3.4313x; 1.3019x over previous
//
#include <hip/hip_runtime.h>

// ============================ EVIDENCE LOG ============================
//  Facts: inputs fp32 time-major as shown; rows/cols int32; d_out FP32
//    (R11 sentinel); out=[out0|out1] each [Tp,n] flat; shown-jnp semantics
//    correct (R12+, absmax 0.0625). Sparse: gather rows[k], scatter cols[k].
//  R12 atomic-scatter: 512 us (WRITE 282 MB = device-atomic RMW amp).
//  R13 CSR(4 tiny kernels)+fused: 197 (fused 105, csr+gaps ~15, floor ~77).
//  R14 single-WG csr_build: 73 us (1 CU serialization, LDS-atomic conflicts)
//    — consolidation anti-pattern. fused_tiled(IT=4) dropped to ~44 us.
//  Fixed harness floor ~77 us (reset memsets + replay) consistent R12-R14.
//  THIS ROUND: parallel CSR micro-kernels (memset for zero) + TRANSPOSED
//    fused kernel: wave = (county x 64 time-lanes); C/D/M transposed to
//    county-major in ws via LDS-tile transpose -> edge data wave-uniform,
//    all gathers coalesced; only out stores scattered (~2 us of L2 traffic).
// ======================================================================

#define SCAN_TH 1024

// ---- CSR build: parallel micro-kernels (R13-proven fast) ----

__global__ void csr_hist(const int* __restrict__ cols, int* __restrict__ counts, int NNZ) {
    int k = blockIdx.x * blockDim.x + threadIdx.x;
    if (k < NNZ) atomicAdd(&counts[cols[k]], 1);
}

__global__ __launch_bounds__(SCAN_TH)
void csr_scan(const int* __restrict__ counts, int* __restrict__ offsets,
              int* __restrict__ cursor, int NC) {
    __shared__ int ssum[SCAN_TH];
    int t = threadIdx.x;
    int chunk = (NC + SCAN_TH - 1) / SCAN_TH;
    int beg = t * chunk, end = min(beg + chunk, NC);
    int local = 0;
    for (int j = beg; j < end; ++j) local += counts[j];
    ssum[t] = local;
    __syncthreads();
    for (int off = 1; off < SCAN_TH; off <<= 1) {
        int v = (t >= off) ? ssum[t - off] : 0;
        __syncthreads();
        ssum[t] += v;
        __syncthreads();
    }
    int run = ssum[t] - local;
    for (int j = beg; j < end; ++j) {
        offsets[j] = run;
        cursor[j]  = run;
        run += counts[j];
    }
    if (t == SCAN_TH - 1) offsets[NC] = ssum[SCAN_TH - 1];
}

__global__ void csr_fill(const int* __restrict__ rows, const int* __restrict__ cols,
                         const float* __restrict__ Bnz, const float* __restrict__ Anz,
                         const float* __restrict__ Hnz,
                         int* __restrict__ cursor, float4* __restrict__ edges, int NNZ) {
    int k = blockIdx.x * blockDim.x + threadIdx.x;
    if (k >= NNZ) return;
    int s = cols[k];                      // scatter target (output county)
    int pos = atomicAdd(&cursor[s], 1);   // bucket order nondet; fp32 noise ~1e-7
    edges[pos] = make_float4(__int_as_float(rows[k]), Bnz[k], Anz[k], Hnz[k]);
}

// ---- Transpose C, D, M[k] ([T,NC] -> [NC,T]) via LDS 64x64 tiles ----
#define TT 64
__global__ void transpose_all(const float* __restrict__ C, const float* __restrict__ D,
                              const float* __restrict__ M,
                              float* __restrict__ Ct, float* __restrict__ Dt,
                              float* __restrict__ Mt, int T, int NC) {
    __shared__ float tile[TT][TT + 1];
    int z = blockIdx.z;
    const float* src;
    float* dst;
    if (z == 0)      { src = C; dst = Ct; }
    else if (z == 1) { src = D; dst = Dt; }
    else             { src = M + (size_t)(z - 2) * T * NC;
                       dst = Mt + (size_t)(z - 2) * NC * T; }
    int tc0 = blockIdx.x * TT;   // county tile origin
    int tt0 = blockIdx.y * TT;   // time tile origin
    int lx = threadIdx.x;        // 0..63
    int ly = threadIdx.y;        // 0..3
    for (int r = ly; r < TT; r += 4) {
        int t = tt0 + r, c = tc0 + lx;
        if (t < T && c < NC) tile[r][lx] = src[(size_t)t * NC + c];
    }
    __syncthreads();
    for (int r = ly; r < TT; r += 4) {
        int c = tc0 + r, t = tt0 + lx;
        if (c < NC && t < T) dst[(size_t)c * T + t] = tile[lx][r];
    }
}

// ---- Fused main kernel: one WAVE per (county, 64-time-chunk) ----
// Edge float4 + cov + offsets are wave-uniform (single-transaction);
// Mt/Ct/Dt reads are lane-coalesced along T. Only out stores scatter.
__global__ void fused_wave(const float* __restrict__ Ct,  // [NC, T]
                           const float* __restrict__ Dt,  // [NC, T]
                           const float* __restrict__ Mt,  // [NMOB, NC, T]
                           const float* __restrict__ cov, // [NCOV, NC]
                           const float* __restrict__ mu,  // [NMOB, 2]
                           const float* __restrict__ nu,  // [NMOB, 2]
                           const float* __restrict__ ups, // [NCOV]
                           const float* __restrict__ zet, // [NCOV]
                           const int* __restrict__ offsets,
                           const float4* __restrict__ edges,
                           float* __restrict__ out0, float* __restrict__ out1,
                           int T, int NC, int NMOB, int NCOV, int TPn, int nChunks) {
    int wid  = (blockIdx.x * blockDim.x + threadIdx.x) >> 6;
    int lane = threadIdx.x & 63;
    if (wid >= NC * nChunks) return;
    int c     = wid / nChunks;
    int chunk = wid - c * nChunks;
    int i     = chunk * 64 + lane;
    bool valid = i < TPn;
    int isafe  = valid ? i : 0;           // safe: isafe+1 <= TPn < T

    float acc0 = 0.f, acc1 = 0.f;

    for (int j = 0; j < NCOV; ++j) {      // wave-uniform broadcast loads
        float cv = cov[(size_t)j * NC + c];
        acc0 += cv * ups[j];
        acc1 += cv * zet[j];
    }
    for (int k = 0; k < NMOB; ++k) {      // coalesced along T, P=2
        const float* mrow = Mt + ((size_t)k * NC + c) * T;
        float m0 = mrow[isafe], m1 = mrow[isafe + 1];
        acc0 += m0 * mu[k * 2] + m1 * mu[k * 2 + 1];
        acc1 += m0 * nu[k * 2] + m1 * nu[k * 2 + 1];
    }
    int e0 = offsets[c], e1 = offsets[c + 1];
    for (int e = e0; e < e1; ++e) {
        float4 E = edges[e];              // wave-uniform (g, B, A, H)
        int g = __float_as_int(E.x);
        const float* crow = Ct + (size_t)g * T;
        const float* drow = Dt + (size_t)g * T;
        float cs = crow[isafe] + crow[isafe + 1];   // coalesced
        float ds = drow[isafe] + drow[isafe + 1];
        acc0 += cs * E.y;
        acc1 += cs * E.w + ds * E.z;
    }
    if (valid) {
        out0[(size_t)i * NC + c] = acc0;  // scattered store (stride NC) — cheap
        out1[(size_t)i * NC + c] = acc1;
    }
}

// Generic fallback (runtime P, untransposed), known-good R13 structure.
__global__ void fused_generic(const float* __restrict__ C, const float* __restrict__ D,
                              const float* __restrict__ M, const float* __restrict__ cov,
                              const float* __restrict__ mu, const float* __restrict__ nu,
                              const float* __restrict__ ups, const float* __restrict__ zet,
                              const int* __restrict__ offsets, const float4* __restrict__ edges,
                              float* __restrict__ out0, float* __restrict__ out1,
                              int T, int NC, int NMOB, int NCOV, int P, int TPn) {
    int idx = blockIdx.x * blockDim.x + threadIdx.x;
    if (idx >= TPn * NC) return;
    int i = idx / NC;
    int c = idx - i * NC;
    float acc0 = 0.f, acc1 = 0.f;
    for (int k = 0; k < NMOB; ++k)
        for (int tau = 0; tau < P; ++tau) {
            float m = M[((size_t)k * T + i + tau) * NC + c];
            acc0 += m * mu[k * P + tau];
            acc1 += m * nu[k * P + tau];
        }
    for (int j = 0; j < NCOV; ++j) {
        float cv = cov[(size_t)j * NC + c];
        acc0 += cv * ups[j];
        acc1 += cv * zet[j];
    }
    int e0 = offsets[c], e1 = offsets[c + 1];
    for (int e = e0; e < e1; ++e) {
        float4 E = edges[e];
        int g = __float_as_int(E.x);
        float cs = 0.f, ds = 0.f;
        for (int tau = 0; tau < P; ++tau) {
            cs += C[(size_t)(i + tau) * NC + g];
            ds += D[(size_t)(i + tau) * NC + g];
        }
        acc0 += cs * E.y;
        acc1 += cs * E.w + ds * E.z;
    }
    out0[idx] = acc0;
    out1[idx] = acc1;
}

extern "C" void kernel_launch(void* const* d_in, const int* in_sizes, int n_in,
                              void* d_out, int out_size, void* d_ws, size_t ws_size,
                              hipStream_t stream) {
    const float* C    = (const float*)d_in[0];
    const float* D    = (const float*)d_in[1];
    const float* M    = (const float*)d_in[2];
    const float* cov  = (const float*)d_in[3];
    const float* Bnz  = (const float*)d_in[4];
    const float* Anz  = (const float*)d_in[5];
    const float* Hnz  = (const float*)d_in[6];
    const float* mu   = (const float*)d_in[7];
    const float* nu   = (const float*)d_in[8];
    const float* ups  = (const float*)d_in[9];
    const float* zet  = (const float*)d_in[10];
    const int*  rows  = (const int*)d_in[11];
    const int*  cols  = (const int*)d_in[12];

    int NCOV = in_sizes[9];                 // 10
    int NC   = in_sizes[3] / NCOV;          // 3144
    int T    = in_sizes[0] / NC;            // 156
    int NMOB = in_sizes[2] / in_sizes[0];   // 6
    int P    = in_sizes[7] / NMOB;          // 2
    int NNZ  = in_sizes[11];                // 31440
    int TPn  = T - P;                       // 154

    float* out0 = (float*)d_out;            // fp32
    float* out1 = out0 + (size_t)TPn * NC;

    // ws carve-up: edges(float4) | offsets | counts | cursor | Ct | Dt | Mt
    float4* edges   = (float4*)d_ws;
    int*    offsets = (int*)(edges + NNZ);
    int*    counts  = offsets + (NC + 1);
    int*    cursor  = counts + NC;
    float*  Ct      = (float*)(cursor + NC);
    float*  Dt      = Ct + (size_t)NC * T;
    float*  Mt      = Dt + (size_t)NC * T;
    size_t  need    = (size_t)((char*)(Mt + (size_t)NMOB * NC * T) - (char*)d_ws);

    const int BS = 256;
    hipMemsetAsync(counts, 0, (size_t)NC * sizeof(int), stream);
    csr_hist<<<(NNZ + BS - 1) / BS, BS, 0, stream>>>(cols, counts, NNZ);
    csr_scan<<<1, SCAN_TH, 0, stream>>>(counts, offsets, cursor, NC);
    csr_fill<<<(NNZ + BS - 1) / BS, BS, 0, stream>>>(
        rows, cols, Bnz, Anz, Hnz, cursor, edges, NNZ);

    if (P == 2 && ws_size >= need) {
        dim3 tb(64, 4);
        dim3 tg((NC + TT - 1) / TT, (T + TT - 1) / TT, 2 + NMOB);
        transpose_all<<<tg, tb, 0, stream>>>(C, D, M, Ct, Dt, Mt, T, NC);

        int nChunks = (TPn + 63) / 64;      // 3
        int nWaves  = NC * nChunks;
        int nThreads = nWaves * 64;
        fused_wave<<<(nThreads + BS - 1) / BS, BS, 0, stream>>>(
            Ct, Dt, Mt, cov, mu, nu, ups, zet, offsets, edges,
            out0, out1, T, NC, NMOB, NCOV, TPn, nChunks);
    } else {
        int n = TPn * NC;
        fused_generic<<<(n + BS - 1) / BS, BS, 0, stream>>>(
            C, D, M, cov, mu, nu, ups, zet, offsets, edges,
            out0, out1, T, NC, NMOB, NCOV, P, TPn);
    }
}

// Round 16
// 141.784 us; speedup vs baseline: 3.6124x; 1.0528x over previous
//
#include <hip/hip_runtime.h>

// ============================ EVIDENCE LOG ============================
//  Facts: inputs fp32 time-major as shown; rows/cols int32; d_out FP32
//    (R11 sentinel); out=[out0|out1] each [Tp,n] flat; shown-jnp semantics
//    correct (absmax 0.0625). Sparse: gather rows[k], scatter cols[k].
//  R12 atomic-scatter 512us (device-atomic RMW amp, WRITE 282MB).
//  R13 CSR+gather-fused 197us (fused 105: latency-bound scalar gathers).
//  R14 single-WG CSR 73us = serialization anti-pattern; fused IT=4 ~44us.
//  R15 transpose-all + wave-per-county 149us. Top-5 = harness 0xAA ws-poison
//    fills (268MB, ~44us) -> fixed overhead ~77us is HARNESS, not ours.
//    Our kernels ~72us: M-transpose wasted 35MB; fused_wave stores scattered.
//  THIS ROUND: transpose only C,D (merged into hist dispatch); sparse_wave
//    writes coalesced ws planes; final_fuse adds mob+cov via native-layout
//    M/cov loads + LDS tile transpose, all loads/stores coalesced. M never
//    transposed. 6 dispatches. Target kernels ~25-30us.
// ======================================================================

#define SCAN_TH 1024

// ---- dispatch 2: csr_hist blocks + C/D transpose blocks (independent) ----
__global__ void hist_and_transposeCD(const int* __restrict__ cols, int* __restrict__ counts,
                                     int NNZ,
                                     const float* __restrict__ C, const float* __restrict__ D,
                                     float* __restrict__ Ct, float* __restrict__ Dt,
                                     int T, int NC, int histBlocks, int cTiles, int tTiles) {
    if ((int)blockIdx.x < histBlocks) {
        int k = blockIdx.x * blockDim.x + threadIdx.x;
        if (k < NNZ) atomicAdd(&counts[cols[k]], 1);
        return;
    }
    __shared__ float tile[64][65];
    int bid = blockIdx.x - histBlocks;
    int z  = bid / (cTiles * tTiles);
    int r  = bid - z * cTiles * tTiles;
    int ct = r / tTiles;
    int tt = r - ct * tTiles;
    const float* src = z ? D : C;
    float* dst = z ? Dt : Ct;
    int lx = threadIdx.x & 63, ly = threadIdx.x >> 6;   // 64 x 4
    int c0 = ct * 64, t0 = tt * 64;
    for (int rr = ly; rr < 64; rr += 4) {
        int t = t0 + rr, c = c0 + lx;
        if (t < T && c < NC) tile[rr][lx] = src[(size_t)t * NC + c];
    }
    __syncthreads();
    for (int rr = ly; rr < 64; rr += 4) {
        int c = c0 + rr, t = t0 + lx;
        if (c < NC && t < T) dst[(size_t)c * T + t] = tile[lx][rr];
    }
}

// ---- dispatch 3: exclusive scan (single WG, 1024 th — cheap at NC=3144) ----
__global__ __launch_bounds__(SCAN_TH)
void csr_scan(const int* __restrict__ counts, int* __restrict__ offsets,
              int* __restrict__ cursor, int NC) {
    __shared__ int ssum[SCAN_TH];
    int t = threadIdx.x;
    int chunk = (NC + SCAN_TH - 1) / SCAN_TH;
    int beg = t * chunk, end = min(beg + chunk, NC);
    int local = 0;
    for (int j = beg; j < end; ++j) local += counts[j];
    ssum[t] = local;
    __syncthreads();
    for (int off = 1; off < SCAN_TH; off <<= 1) {
        int v = (t >= off) ? ssum[t - off] : 0;
        __syncthreads();
        ssum[t] += v;
        __syncthreads();
    }
    int run = ssum[t] - local;
    for (int j = beg; j < end; ++j) {
        offsets[j] = run;
        cursor[j]  = run;
        run += counts[j];
    }
    if (t == SCAN_TH - 1) offsets[NC] = ssum[SCAN_TH - 1];
}

// ---- dispatch 4: CSR fill (float4 edges: g, B, A, H) ----
__global__ void csr_fill(const int* __restrict__ rows, const int* __restrict__ cols,
                         const float* __restrict__ Bnz, const float* __restrict__ Anz,
                         const float* __restrict__ Hnz,
                         int* __restrict__ cursor, float4* __restrict__ edges, int NNZ) {
    int k = blockIdx.x * blockDim.x + threadIdx.x;
    if (k >= NNZ) return;
    int s = cols[k];
    int pos = atomicAdd(&cursor[s], 1);   // bucket order nondet; fp32 noise ~1e-7
    edges[pos] = make_float4(__int_as_float(rows[k]), Bnz[k], Anz[k], Hnz[k]);
}

// ---- dispatch 5: sparse term only. wave = (county, 64 time-lanes).
// Edge data wave-uniform; Ct/Dt loads lane-coalesced; ws stores coalesced
// county-major [NC, TPn] (overwrite, no init needed). ----
__global__ void sparse_wave(const float* __restrict__ Ct, const float* __restrict__ Dt,
                            const int* __restrict__ offsets, const float4* __restrict__ edges,
                            float* __restrict__ wsS0, float* __restrict__ wsS1,
                            int T, int TPn, int nChunks, int nWaves) {
    int gtid = blockIdx.x * blockDim.x + threadIdx.x;
    int wid = gtid >> 6, lane = threadIdx.x & 63;
    if (wid >= nWaves) return;
    int c = wid / nChunks;
    int chunk = wid - c * nChunks;
    int i = chunk * 64 + lane;
    bool valid = i < TPn;
    int isafe = valid ? i : 0;            // isafe+1 <= TPn < T: safe
    float a0 = 0.f, a1 = 0.f;
    int e0 = offsets[c], e1 = offsets[c + 1];
    for (int e = e0; e < e1; ++e) {
        float4 E = edges[e];              // wave-uniform broadcast
        int g = __float_as_int(E.x);
        const float* cr = Ct + (size_t)g * T;
        const float* dr = Dt + (size_t)g * T;
        float cs = cr[isafe] + cr[isafe + 1];
        float ds = dr[isafe] + dr[isafe + 1];
        a0 += cs * E.y;
        a1 += cs * E.w + ds * E.z;
    }
    if (valid) {
        wsS0[(size_t)c * TPn + i] = a0;
        wsS1[(size_t)c * TPn + i] = a1;
    }
}

// ---- dispatch 6: final fuse. 32x32 (i x c) LDS tiles: read wsS coalesced
// along i, add cov+mob with NATIVE-layout coalesced loads (lane->c), write
// out coalesced along c. P=2 specialized. ----
#define FTI 32
#define FTC 32
__global__ void final_fuse(const float* __restrict__ wsS0, const float* __restrict__ wsS1,
                           const float* __restrict__ M,   // [NMOB, T, NC] native
                           const float* __restrict__ cov, // [NCOV, NC]
                           const float* __restrict__ mu,  // [NMOB, 2]
                           const float* __restrict__ nu,
                           const float* __restrict__ ups, const float* __restrict__ zet,
                           float* __restrict__ out0, float* __restrict__ out1,
                           int T, int NC, int NMOB, int NCOV, int TPn, int cTiles) {
    __shared__ float s0[FTI][FTC + 1], s1[FTI][FTC + 1];
    int bi = blockIdx.x / cTiles;
    int bc = blockIdx.x - bi * cTiles;
    int i0 = bi * FTI, c0 = bc * FTC;
    int tid = threadIdx.x;                // 256

    // phase 1: lanes along i (32-wide coalesced), 8 c-rows, x4
    {
        int li = tid & 31;
        int lc0 = tid >> 5;
        int i = i0 + li;
        for (int cc = lc0; cc < FTC; cc += 8) {
            int c = c0 + cc;
            float v0 = 0.f, v1 = 0.f;
            if (c < NC && i < TPn) {
                v0 = wsS0[(size_t)c * TPn + i];
                v1 = wsS1[(size_t)c * TPn + i];
            }
            s0[li][cc] = v0;
            s1[li][cc] = v1;
        }
    }
    __syncthreads();

    // phase 2: lanes along c (32-wide coalesced), fixed c per thread, 4 i vals
    int lc = tid & 31;
    int ri = tid >> 5;                    // 0..7
    int c = c0 + lc;
    if (c >= NC) return;

    float cv0 = 0.f, cv1 = 0.f;
    for (int j = 0; j < NCOV; ++j) {
        float cv = cov[(size_t)j * NC + c];
        cv0 += cv * ups[j];
        cv1 += cv * zet[j];
    }
    for (int ii = ri; ii < FTI; ii += 8) {
        int i = i0 + ii;
        if (i >= TPn) break;
        float a0 = s0[ii][lc] + cv0;
        float a1 = s1[ii][lc] + cv1;
        for (int k = 0; k < NMOB; ++k) {
            const float* mb = M + (size_t)k * T * NC;
            float m0 = mb[(size_t)i * NC + c];
            float m1 = mb[(size_t)(i + 1) * NC + c];
            a0 += m0 * mu[k * 2] + m1 * mu[k * 2 + 1];
            a1 += m0 * nu[k * 2] + m1 * nu[k * 2 + 1];
        }
        out0[(size_t)i * NC + c] = a0;
        out1[(size_t)i * NC + c] = a1;
    }
}

// Generic fallback (runtime P, untransposed), known-good R13 structure.
__global__ void fused_generic(const float* __restrict__ C, const float* __restrict__ D,
                              const float* __restrict__ M, const float* __restrict__ cov,
                              const float* __restrict__ mu, const float* __restrict__ nu,
                              const float* __restrict__ ups, const float* __restrict__ zet,
                              const int* __restrict__ offsets, const float4* __restrict__ edges,
                              float* __restrict__ out0, float* __restrict__ out1,
                              int T, int NC, int NMOB, int NCOV, int P, int TPn) {
    int idx = blockIdx.x * blockDim.x + threadIdx.x;
    if (idx >= TPn * NC) return;
    int i = idx / NC;
    int c = idx - i * NC;
    float acc0 = 0.f, acc1 = 0.f;
    for (int k = 0; k < NMOB; ++k)
        for (int tau = 0; tau < P; ++tau) {
            float m = M[((size_t)k * T + i + tau) * NC + c];
            acc0 += m * mu[k * P + tau];
            acc1 += m * nu[k * P + tau];
        }
    for (int j = 0; j < NCOV; ++j) {
        float cv = cov[(size_t)j * NC + c];
        acc0 += cv * ups[j];
        acc1 += cv * zet[j];
    }
    int e0 = offsets[c], e1 = offsets[c + 1];
    for (int e = e0; e < e1; ++e) {
        float4 E = edges[e];
        int g = __float_as_int(E.x);
        float cs = 0.f, ds = 0.f;
        for (int tau = 0; tau < P; ++tau) {
            cs += C[(size_t)(i + tau) * NC + g];
            ds += D[(size_t)(i + tau) * NC + g];
        }
        acc0 += cs * E.y;
        acc1 += cs * E.w + ds * E.z;
    }
    out0[idx] = acc0;
    out1[idx] = acc1;
}

extern "C" void kernel_launch(void* const* d_in, const int* in_sizes, int n_in,
                              void* d_out, int out_size, void* d_ws, size_t ws_size,
                              hipStream_t stream) {
    const float* C    = (const float*)d_in[0];
    const float* D    = (const float*)d_in[1];
    const float* M    = (const float*)d_in[2];
    const float* cov  = (const float*)d_in[3];
    const float* Bnz  = (const float*)d_in[4];
    const float* Anz  = (const float*)d_in[5];
    const float* Hnz  = (const float*)d_in[6];
    const float* mu   = (const float*)d_in[7];
    const float* nu   = (const float*)d_in[8];
    const float* ups  = (const float*)d_in[9];
    const float* zet  = (const float*)d_in[10];
    const int*  rows  = (const int*)d_in[11];
    const int*  cols  = (const int*)d_in[12];

    int NCOV = in_sizes[9];                 // 10
    int NC   = in_sizes[3] / NCOV;          // 3144
    int T    = in_sizes[0] / NC;            // 156
    int NMOB = in_sizes[2] / in_sizes[0];   // 6
    int P    = in_sizes[7] / NMOB;          // 2
    int NNZ  = in_sizes[11];                // 31440
    int TPn  = T - P;                       // 154

    float* out0 = (float*)d_out;            // fp32
    float* out1 = out0 + (size_t)TPn * NC;

    // ws carve-up: edges | offsets | counts | cursor | Ct | Dt | wsS0 | wsS1
    float4* edges   = (float4*)d_ws;
    int*    offsets = (int*)(edges + NNZ);
    int*    counts  = offsets + (NC + 1);
    int*    cursor  = counts + NC;
    float*  Ct      = (float*)(cursor + NC);
    float*  Dt      = Ct + (size_t)NC * T;
    float*  wsS0    = Dt + (size_t)NC * T;
    float*  wsS1    = wsS0 + (size_t)NC * TPn;
    size_t  need    = (size_t)((char*)(wsS1 + (size_t)NC * TPn) - (char*)d_ws);

    const int BS = 256;
    hipMemsetAsync(counts, 0, (size_t)NC * sizeof(int), stream);

    if (P == 2 && ws_size >= need) {
        int histBlocks = (NNZ + BS - 1) / BS;
        int cT64 = (NC + 63) / 64, tT64 = (T + 63) / 64;
        hist_and_transposeCD<<<histBlocks + 2 * cT64 * tT64, BS, 0, stream>>>(
            cols, counts, NNZ, C, D, Ct, Dt, T, NC, histBlocks, cT64, tT64);

        csr_scan<<<1, SCAN_TH, 0, stream>>>(counts, offsets, cursor, NC);
        csr_fill<<<(NNZ + BS - 1) / BS, BS, 0, stream>>>(
            rows, cols, Bnz, Anz, Hnz, cursor, edges, NNZ);

        int nChunks = (TPn + 63) / 64;      // 3
        int nWaves  = NC * nChunks;
        sparse_wave<<<(nWaves * 64 + BS - 1) / BS, BS, 0, stream>>>(
            Ct, Dt, offsets, edges, wsS0, wsS1, T, TPn, nChunks, nWaves);

        int iTiles = (TPn + FTI - 1) / FTI; // 5
        int cTiles = (NC + FTC - 1) / FTC;  // 99
        final_fuse<<<iTiles * cTiles, BS, 0, stream>>>(
            wsS0, wsS1, M, cov, mu, nu, ups, zet,
            out0, out1, T, NC, NMOB, NCOV, TPn, cTiles);
    } else {
        // fallback: plain CSR + generic fused (no transpose path)
        csr_hist_only:;
        hist_and_transposeCD<<<(NNZ + BS - 1) / BS, BS, 0, stream>>>(
            cols, counts, NNZ, C, D, (float*)d_ws, (float*)d_ws, T, NC,
            (NNZ + BS - 1) / BS, 0, 0);   // hist blocks only, no transpose blocks
        csr_scan<<<1, SCAN_TH, 0, stream>>>(counts, offsets, cursor, NC);
        csr_fill<<<(NNZ + BS - 1) / BS, BS, 0, stream>>>(
            rows, cols, Bnz, Anz, Hnz, cursor, edges, NNZ);
        int n = TPn * NC;
        fused_generic<<<(n + BS - 1) / BS, BS, 0, stream>>>(
            C, D, M, cov, mu, nu, ups, zet, offsets, edges,
            out0, out1, T, NC, NMOB, NCOV, P, TPn);
    }
}